// Round 6
// baseline (506.955 us; speedup 1.0000x reference)
//
#include <hip/hip_runtime.h>
#include <math.h>

#define N_NODES 50000
#define N_EDGES 1000000
#define CCH     32
#define ROW     288           // 32 + 96 + 160
#define SCAN_BLOCKS 196       // ceil(50000/256)

// ---------------------------------------------------------------------------
// K1: degree histogram over receivers.
// ---------------------------------------------------------------------------
__global__ __launch_bounds__(256) void hist_kernel(
    const int* __restrict__ edge_index, int* __restrict__ deg)
{
    const int e = blockIdx.x * 256 + threadIdx.x;
    if (e >= N_EDGES) return;
    atomicAdd(&deg[edge_index[N_EDGES + e]], 1);
}

// ---------------------------------------------------------------------------
// K2: one-pass scan, no cross-block communication. Block b redundantly sums
// deg[0..256b) (<=200 KB coalesced L2 reads), adds its local Hillis-Steele
// scan, writes offset/cursor. Last block also writes offset[N] = E.
// ---------------------------------------------------------------------------
__global__ __launch_bounds__(256) void scan_kernel(
    const int* __restrict__ deg, int* __restrict__ offset, int* __restrict__ cursor)
{
    __shared__ int s[256];
    __shared__ int s_base;
    const int t = threadIdx.x;
    const int b = blockIdx.x;

    // redundant prefix-of-block sum
    int part = 0;
    for (int i = t; i < b * 256; i += 256) part += deg[i];
    s[t] = part;
    __syncthreads();
    #pragma unroll
    for (int ofs = 128; ofs > 0; ofs >>= 1) {
        if (t < ofs) s[t] += s[t + ofs];
        __syncthreads();
    }
    if (t == 0) s_base = s[0];
    __syncthreads();
    const int base = s_base;
    __syncthreads();

    // local scan of this block's 256 degrees
    const int gid = b * 256 + t;
    const int v = (gid < N_NODES) ? deg[gid] : 0;
    s[t] = v;
    __syncthreads();
    for (int ofs = 1; ofs < 256; ofs <<= 1) {
        int w = (t >= ofs) ? s[t - ofs] : 0;
        __syncthreads();
        s[t] += w;
        __syncthreads();
    }
    const int excl = s[t] - v;
    if (gid < N_NODES) {
        offset[gid] = base + excl;
        cursor[gid] = base + excl;
    }
    if (b == SCAN_BLOCKS - 1 && t == 255) offset[N_NODES] = base + s[255];
}

// ---------------------------------------------------------------------------
// K3: fused MLP + pack into CSR order. One thread per edge, all input reads
// sequential/coalesced. Writes one 64-B record per edge at its CSR slot:
//   [ h2*inv6 (6) | y0 (1) | y1 (3) | y2 (5) | sender-as-bits (1) ]
// ---------------------------------------------------------------------------
__global__ __launch_bounds__(256) void pack_kernel(
    const float* __restrict__ lenght,     // (E, 8)
    const float* __restrict__ edge_attr,  // (E, 9)
    const int*   __restrict__ edge_index, // (2, E)
    const float* __restrict__ fw0,        // (8, 6)
    const float* __restrict__ fw1,        // (6, 6)
    const float* __restrict__ fw2,        // (6, 6)
    int*         __restrict__ cursor,     // (N)
    float4*      __restrict__ rec)        // (E, 4 x float4)
{
    __shared__ float s_w[120];
    for (int i = threadIdx.x; i < 120; i += 256)
        s_w[i] = (i < 48) ? fw0[i] : (i < 84) ? fw1[i - 48] : fw2[i - 84];
    __syncthreads();
    const float* sw0 = s_w;
    const float* sw1 = s_w + 48;
    const float* sw2 = s_w + 84;

    const int e = blockIdx.x * 256 + threadIdx.x;
    if (e >= N_EDGES) return;

    const float inv8 = 0.35355339059327373f;   // 1/sqrt(8)
    const float inv6 = 0.4082482904638631f;    // 1/sqrt(6)

    float len[8];
    const float4 l0 = ((const float4*)(lenght + (long long)e * 8))[0];
    const float4 l1 = ((const float4*)(lenght + (long long)e * 8))[1];
    len[0]=l0.x; len[1]=l0.y; len[2]=l0.z; len[3]=l0.w;
    len[4]=l1.x; len[5]=l1.y; len[6]=l1.z; len[7]=l1.w;

    float h0[6], h1[6], h2[6];
    #pragma unroll
    for (int j = 0; j < 6; ++j) {
        float a = 0.f;
        #pragma unroll
        for (int k = 0; k < 8; ++k) a += len[k] * sw0[k * 6 + j];
        a *= inv8;
        h0[j] = a / (1.f + __expf(-a));
    }
    #pragma unroll
    for (int j = 0; j < 6; ++j) {
        float a = 0.f;
        #pragma unroll
        for (int k = 0; k < 6; ++k) a += h0[k] * sw1[k * 6 + j];
        a *= inv6;
        h1[j] = a / (1.f + __expf(-a));
    }
    #pragma unroll
    for (int j = 0; j < 6; ++j) {
        float a = 0.f;
        #pragma unroll
        for (int k = 0; k < 6; ++k) a += h1[k] * sw2[k * 6 + j];
        a *= inv6;
        h2[j] = a * inv6 / (1.f + __expf(-a));   // fold final-layer 1/sqrt(6)
    }

    const float* ea = edge_attr + (long long)e * 9;
    float y[9];
    #pragma unroll
    for (int i = 0; i < 9; ++i) y[i] = ea[i];

    const int snd = edge_index[e];
    const int r   = edge_index[N_EDGES + e];
    const int p   = atomicAdd(&cursor[r], 1);

    float4* rp = rec + (long long)p * 4;
    rp[0] = make_float4(h2[0], h2[1], h2[2], h2[3]);
    rp[1] = make_float4(h2[4], h2[5], y[0], y[1]);
    rp[2] = make_float4(y[2], y[3], y[4], y[5]);
    rp[3] = make_float4(y[6], y[7], y[8], __int_as_float(snd));
}

// ---------------------------------------------------------------------------
// K4: gather + message + segment-sum + node linear.
// One 64-lane wave handles FOUR consecutive nodes (prologue/epilogue
// amortized; next node's first record prefetched before each epilogue).
// Half-wave h handles edges j = h, h+2, ...; lane = channel c.
// deg comes from offset[i+1]-offset[i] (offset has N+1 entries).
// ---------------------------------------------------------------------------
__global__ __launch_bounds__(256) void gather_kernel(
    const float4* __restrict__ rec,          // (E, 4 x float4)
    const float*  __restrict__ node_features,// (N, 32)
    const int*    __restrict__ offset,       // (N+1)
    const float*  __restrict__ fw3,          // (6, 96)
    const float*  __restrict__ lw0,          // (32, 32)
    const float*  __restrict__ lw1,          // (32, 32)
    const float*  __restrict__ lw2,          // (32, 32)
    float*        __restrict__ out)          // (N, 288)
{
    __shared__ float s_lw0[1024], s_lw1[1024], s_lw2[1024];
    for (int i = threadIdx.x; i < 1024; i += 256) {
        s_lw0[i] = lw0[i];
        s_lw1[i] = lw1[i];
        s_lw2[i] = lw2[i];
    }
    __syncthreads();

    const int wave = threadIdx.x >> 6;
    const int l    = threadIdx.x & 63;
    const int c    = l & 31;
    const int h    = l >> 5;
    const int wid  = blockIdx.x * 4 + wave;   // 12500 waves
    const int base = wid * 4;                 // first of this wave's 4 nodes

    float f3a[6], f3b[6], f3c[6];
    #pragma unroll
    for (int k = 0; k < 6; ++k) {
        f3a[k] = fw3[k * 96 + c];
        f3b[k] = fw3[k * 96 + 32 + c];
        f3c[k] = fw3[k * 96 + 64 + c];
    }

    int offs[5];
    {
        const int4 o4 = *(const int4*)(offset + base);
        offs[0] = o4.x; offs[1] = o4.y; offs[2] = o4.z; offs[3] = o4.w;
        offs[4] = offset[base + 4];
    }

    // prefetch node 0's first record
    float4 r0, r1, r2, r3;
    if (h < offs[1] - offs[0]) {
        const float4* rp = rec + (long long)(offs[0] + h) * 4;
        r0 = rp[0]; r1 = rp[1]; r2 = rp[2]; r3 = rp[3];
    }

    const float inv32 = 0.17677669529663687f;  // 1/sqrt(32)
    const int d = c;

    #pragma unroll 1
    for (int k = 0; k < 4; ++k) {
        const int off = offs[k];
        const int dg  = offs[k + 1] - off;

        float acc[9] = {0.f,0.f,0.f,0.f,0.f,0.f,0.f,0.f,0.f};
        float xq = 0.f;
        if (h < dg)
            xq = node_features[(long long)__float_as_int(r3.w) * CCH + c];

        int j = h;
        while (j < dg) {
            const int jn = j + 2;
            float4 n0, n1, n2, n3;
            if (jn < dg) {                          // prefetch next record
                const float4* rp = rec + (long long)(off + jn) * 4;
                n0 = rp[0]; n1 = rp[1]; n2 = rp[2]; n3 = rp[3];
            }

            const float w0c = r0.x*f3a[0] + r0.y*f3a[1] + r0.z*f3a[2]
                            + r0.w*f3a[3] + r1.x*f3a[4] + r1.y*f3a[5];
            const float w1c = r0.x*f3b[0] + r0.y*f3b[1] + r0.z*f3b[2]
                            + r0.w*f3b[3] + r1.x*f3b[4] + r1.y*f3b[5];
            const float w2c = r0.x*f3c[0] + r0.y*f3c[1] + r0.z*f3c[2]
                            + r0.w*f3c[3] + r1.x*f3c[4] + r1.y*f3c[5];

            const float x = xq;
            acc[0] += (w0c * x) * r1.z;
            const float a1 = w1c * x;
            acc[1] += a1 * r1.w;
            acc[2] += a1 * r2.x;
            acc[3] += a1 * r2.y;
            const float a2 = w2c * x;
            acc[4] += a2 * r2.z;
            acc[5] += a2 * r2.w;
            acc[6] += a2 * r3.x;
            acc[7] += a2 * r3.y;
            acc[8] += a2 * r3.z;

            if (jn < dg)
                xq = node_features[(long long)__float_as_int(n3.w) * CCH + c];
            r0 = n0; r1 = n1; r2 = n2; r3 = n3;
            j = jn;
        }

        // prefetch NEXT node's first record; epilogue below hides its latency
        if (k < 3) {
            if (h < offs[k + 2] - offs[k + 1]) {
                const float4* rp = rec + (long long)(offs[k + 1] + h) * 4;
                r0 = rp[0]; r1 = rp[1]; r2 = rp[2]; r3 = rp[3];
            }
        }

        // combine halves: lanes 0..31 hold msg[c][0..8]
        #pragma unroll
        for (int q = 0; q < 9; ++q) acc[q] += __shfl_down(acc[q], 32);

        // node linear via shfl transpose; halves split the cc loop
        float o0 = 0.f;
        float o1[3] = {0.f, 0.f, 0.f};
        float o2[5] = {0.f, 0.f, 0.f, 0.f, 0.f};
        for (int cc = h * 16; cc < h * 16 + 16; ++cc) {
            const float m0 = __shfl(acc[0], cc);
            const float m1 = __shfl(acc[1], cc);
            const float m2 = __shfl(acc[2], cc);
            const float m3 = __shfl(acc[3], cc);
            const float m4 = __shfl(acc[4], cc);
            const float m5 = __shfl(acc[5], cc);
            const float m6 = __shfl(acc[6], cc);
            const float m7 = __shfl(acc[7], cc);
            const float m8 = __shfl(acc[8], cc);
            o0 += m0 * s_lw0[cc * 32 + d];
            const float w1 = s_lw1[cc * 32 + d];
            o1[0] += m1 * w1; o1[1] += m2 * w1; o1[2] += m3 * w1;
            const float w2 = s_lw2[cc * 32 + d];
            o2[0] += m4 * w2; o2[1] += m5 * w2; o2[2] += m6 * w2;
            o2[3] += m7 * w2; o2[4] += m8 * w2;
        }

        o0 += __shfl_down(o0, 32);
        #pragma unroll
        for (int i = 0; i < 3; ++i) o1[i] += __shfl_down(o1[i], 32);
        #pragma unroll
        for (int i = 0; i < 5; ++i) o2[i] += __shfl_down(o2[i], 32);

        if (h == 0) {
            float* op = out + (long long)(base + k) * ROW;
            op[d] = o0 * inv32;
            #pragma unroll
            for (int i = 0; i < 3; ++i) op[32 + d * 3 + i] = o1[i] * inv32;
            #pragma unroll
            for (int i = 0; i < 5; ++i) op[128 + d * 5 + i] = o2[i] * inv32;
        }
    }
}

extern "C" void kernel_launch(void* const* d_in, const int* in_sizes, int n_in,
                              void* d_out, int out_size, void* d_ws, size_t ws_size,
                              hipStream_t stream)
{
    const float* lenght = (const float*)d_in[0];
    const float* nf     = (const float*)d_in[1];
    const float* ea     = (const float*)d_in[2];
    const int*   ei     = (const int*)d_in[3];
    const float* fw0    = (const float*)d_in[4];
    const float* fw1    = (const float*)d_in[5];
    const float* fw2    = (const float*)d_in[6];
    const float* fw3    = (const float*)d_in[7];
    const float* lw0    = (const float*)d_in[8];
    const float* lw1    = (const float*)d_in[9];
    const float* lw2    = (const float*)d_in[10];
    float* out = (float*)d_out;

    // workspace layout
    char* ws = (char*)d_ws;
    float4* rec = (float4*)ws; ws += (size_t)N_EDGES * 4 * sizeof(float4);  // 64 MB
    int* deg    = (int*)ws;    ws += (size_t)N_NODES * sizeof(int);
    int* offset = (int*)ws;    ws += (size_t)(N_NODES + 4) * sizeof(int);
    int* cursor = (int*)ws;    ws += (size_t)N_NODES * sizeof(int);

    hipMemsetAsync(deg, 0, (size_t)N_NODES * sizeof(int), stream);

    const int EB = (N_EDGES + 255) / 256;
    hist_kernel  <<<EB, 256, 0, stream>>>(ei, deg);
    scan_kernel  <<<SCAN_BLOCKS, 256, 0, stream>>>(deg, offset, cursor);
    pack_kernel  <<<EB, 256, 0, stream>>>(lenght, ea, ei, fw0, fw1, fw2, cursor, rec);
    gather_kernel<<<N_NODES / 16, 256, 0, stream>>>(
        rec, nf, offset, fw3, lw0, lw1, lw2, out);
}